// Round 2
// baseline (531.604 us; speedup 1.0000x reference)
//
#include <hip/hip_runtime.h>
#include <math.h>

// EM routing, fully fused: one block per (b, l) output position, 512 threads.
// A=32, B=32, PSIZE=16 (4x4), K=3, STRIDE=2, PAD=1, ITERS=3.
// Input 14x14 -> output 7x7 (l = 49). kkA = 9*32 = 288.

#define B_      32
#define KKA_    288
#define L_      49
#define OH_     7
#define EPSF    1e-12f
#define RST     292              // padded k-stride of r_t rows
#define LOG_LN2PI 0.60861006f    // log(log(2*pi))

__global__ __launch_bounds__(512, 4) void em_routing_kernel(
    const float* __restrict__ a_in,   // (8, 32, 14, 14)
    const float* __restrict__ pose,   // (8, 512, 14, 14)
    const float* __restrict__ W,      // (288, 32, 4, 4)
    const float* __restrict__ beta_u, // (32)
    const float* __restrict__ beta_a, // (32)
    float* __restrict__ out)          // a_o (8,32,7,7) then pose_out (8,512,7,7)
{
    __shared__ float pu_lds[KKA_ * 16];   // 18432 B  pu[k][p], p = i*4+j
    __shared__ float au_lds[KKA_];        //  1152 B
    __shared__ float r_t[B_ * RST];       // 37376 B  r/coeff/ln_ap, [c][k] padded
    __shared__ float mu_t[16 * 33];       //  2112 B  mu[p][c]
    __shared__ float is2_t[16 * 33];      //  2112 B  0.5/sigma^2 [p][c]
    __shared__ float m1_lds[B_];          //   128 B  per-c ln_p const + ln a

    const int tid = threadIdx.x;
    const int bl = blockIdx.x;
    const int b  = bl / L_;
    const int l  = bl % L_;
    const int oy = l / OH_, ox = l % OH_;

    // ---- stage pu (pose unfold patch) ----
    for (int q = tid; q < KKA_ * 16; q += 512) {
        const int k = q >> 4, p = q & 15;
        const int a = k & 31, kki = k >> 5;
        const int ki = kki / 3, kj = kki % 3;
        const int iy = oy * 2 + ki - 1, ix = ox * 2 + kj - 1;
        float v = 0.f;
        if ((unsigned)iy < 14u && (unsigned)ix < 14u)
            v = pose[(b * 512 + a * 16 + p) * 196 + iy * 14 + ix];
        pu_lds[q] = v;
    }
    // ---- stage au (activation unfold) ----
    if (tid < KKA_) {
        const int k = tid;
        const int a = k & 31, kki = k >> 5;
        const int ki = kki / 3, kj = kki % 3;
        const int iy = oy * 2 + ki - 1, ix = ox * 2 + kj - 1;
        float v = 0.f;
        if ((unsigned)iy < 14u && (unsigned)ix < 14u)
            v = a_in[(b * 32 + a) * 196 + iy * 14 + ix];
        au_lds[k] = v;
    }
    // ---- init r = 1 ----
    for (int q = tid; q < B_ * RST; q += 512) r_t[q] = 1.0f;
    __syncthreads();

    // thread mappings
    const int c   = tid >> 4;       // 0..31  (step1 + P23)
    const int sub = tid & 15;       // 0..15
    const int kh  = sub & 1;        // k-half for P23
    const int pp  = sub >> 1;       // p-pair 0..7
    const int p0  = pp << 1;        // even p
    const int i4  = p0 >> 2;        // pose-matrix row
    const int m0  = (pp & 1) << 1;  // 0 or 2
    const int cQ  = tid & 31;       // P4: capsule
    const int kg  = tid >> 5;       // P4: k-group 0..15

    const float bu_c = beta_u[c];
    const float ba_c = beta_a[c];

    for (int it = 0; it < 3; ++it) {
        const float lam = (it == 0) ? 0.0005f : ((it == 1) ? 0.000975f : 0.00142625f);

        // ---- step 1: r_sum[c] and coeff (in place over r_t), 16 lanes/c ----
        const int rbase = c * RST + sub * 18;
        const int abase = sub * 18;
        float part = 0.f;
        #pragma unroll
        for (int t = 0; t < 18; t += 2) {
            const float2 r2 = *(const float2*)&r_t[rbase + t];
            const float2 a2 = *(const float2*)&au_lds[abase + t];
            part += r2.x * a2.x + r2.y * a2.y;
        }
        part += __shfl_xor(part, 1);
        part += __shfl_xor(part, 2);
        part += __shfl_xor(part, 4);
        part += __shfl_xor(part, 8);
        const float rsum = part;                 // rs[c]
        const float invr = 1.0f / (rsum + EPSF);
        #pragma unroll
        for (int t = 0; t < 18; t += 2) {
            float2 r2 = *(const float2*)&r_t[rbase + t];
            const float2 a2 = *(const float2*)&au_lds[abase + t];
            r2.x *= a2.x * invr; r2.y *= a2.y * invr;
            *(float2*)&r_t[rbase + t] = r2;
        }
        __syncthreads();

        // ---- P23: mu and E[x^2] for (c, p0), (c, p0+1); k split over kh ----
        float S10 = 0.f, S11 = 0.f, S20 = 0.f, S21 = 0.f;
        const int kbeg = kh * 144;
        for (int k0 = kbeg; k0 < kbeg + 144; k0 += 4) {
            const float4 cf4 = *(const float4*)&r_t[c * RST + k0];
            #pragma unroll
            for (int u = 0; u < 4; ++u) {
                const int k = k0 + u;
                const float cf = (&cf4.x)[u];
                const float4 pu4 = *(const float4*)&pu_lds[(k << 4) + (i4 << 2)];
                const float* Wk = W + (k * 512 + c * 16 + m0);
                const float2 w0 = *(const float2*)(Wk);
                const float2 w1 = *(const float2*)(Wk + 4);
                const float2 w2 = *(const float2*)(Wk + 8);
                const float2 w3 = *(const float2*)(Wk + 12);
                const float v0 = pu4.x * w0.x + pu4.y * w1.x + pu4.z * w2.x + pu4.w * w3.x;
                const float v1 = pu4.x * w0.y + pu4.y * w1.y + pu4.z * w2.y + pu4.w * w3.y;
                const float cv0 = cf * v0, cv1 = cf * v1;
                S10 += cv0; S20 += cv0 * v0;
                S11 += cv1; S21 += cv1 * v1;
            }
        }
        // combine the two k-halves (kh is bit 0 of tid)
        S10 += __shfl_xor(S10, 1);
        S11 += __shfl_xor(S11, 1);
        S20 += __shfl_xor(S20, 1);
        S21 += __shfl_xor(S21, 1);
        const float mu0 = S10, mu1 = S11;
        const float ss0 = fmaxf(S20 - mu0 * mu0, 0.f) + EPSF;
        const float ss1 = fmaxf(S21 - mu1 * mu1, 0.f) + EPSF;
        float Ls = __logf(ss0) + __logf(ss1);
        Ls += __shfl_xor(Ls, 2);
        Ls += __shfl_xor(Ls, 4);
        Ls += __shfl_xor(Ls, 8);                 // sum_p log(ss)
        const float cost = rsum * (16.f * bu_c + 0.5f * Ls);
        const float aout = 1.f / (1.f + __expf(-(lam * (ba_c - cost))));

        if (it == 2) {
            // ---- write outputs (kh==0 lane of each pair) ----
            if (kh == 0) {
                const int obase = 12544 + (b * 512 + (c << 4) + p0) * 49 + l;
                out[obase]      = mu0;
                out[obase + 49] = mu1;
                if (pp == 0) out[(b * 32 + c) * 49 + l] = aout;
            }
        } else {
            if (kh == 0) {
                mu_t[p0 * 33 + c]        = mu0;
                mu_t[(p0 + 1) * 33 + c]  = mu1;
                is2_t[p0 * 33 + c]       = 0.5f / ss0;
                is2_t[(p0 + 1) * 33 + c] = 0.5f / ss1;
                if (pp == 0)
                    m1_lds[c] = -0.5f * (Ls + 16.f * LOG_LN2PI) + __logf(aout);
            }
            __syncthreads();

            // ---- P4: ln_ap[k][c] -> r_t  (kg = 0..15, 18 k's each) ----
            float mu_r[16], is2_r[16];
            #pragma unroll
            for (int p = 0; p < 16; ++p) {
                mu_r[p]  = mu_t[p * 33 + cQ];
                is2_r[p] = is2_t[p * 33 + cQ];
            }
            const float m1c = m1_lds[cQ];
            for (int j = 0; j < 18; ++j) {
                const int k = kg + (j << 4);
                const float* Wk = W + (k * 512 + cQ * 16);
                const float4 wr0 = *(const float4*)(Wk);
                const float4 wr1 = *(const float4*)(Wk + 4);
                const float4 wr2 = *(const float4*)(Wk + 8);
                const float4 wr3 = *(const float4*)(Wk + 12);
                float q = 0.f;
                #pragma unroll
                for (int i = 0; i < 4; ++i) {
                    const float4 pui = *(const float4*)&pu_lds[(k << 4) + (i << 2)];
                    float vv, d;
                    vv = pui.x * wr0.x + pui.y * wr1.x + pui.z * wr2.x + pui.w * wr3.x;
                    d = vv - mu_r[i * 4 + 0]; q += d * d * is2_r[i * 4 + 0];
                    vv = pui.x * wr0.y + pui.y * wr1.y + pui.z * wr2.y + pui.w * wr3.y;
                    d = vv - mu_r[i * 4 + 1]; q += d * d * is2_r[i * 4 + 1];
                    vv = pui.x * wr0.z + pui.y * wr1.z + pui.z * wr2.z + pui.w * wr3.z;
                    d = vv - mu_r[i * 4 + 2]; q += d * d * is2_r[i * 4 + 2];
                    vv = pui.x * wr0.w + pui.y * wr1.w + pui.z * wr2.w + pui.w * wr3.w;
                    d = vv - mu_r[i * 4 + 3]; q += d * d * is2_r[i * 4 + 3];
                }
                r_t[cQ * RST + k] = m1c - q;
            }
            __syncthreads();

            // ---- softmax over c for each k -> new r ----
            if (tid < KKA_) {
                const int k = tid;
                float vals[32];
                float mx = -3.0e38f;
                #pragma unroll
                for (int cc = 0; cc < 32; ++cc) {
                    vals[cc] = r_t[cc * RST + k];
                    mx = fmaxf(mx, vals[cc]);
                }
                float s = 0.f;
                #pragma unroll
                for (int cc = 0; cc < 32; ++cc) {
                    vals[cc] = __expf(vals[cc] - mx);
                    s += vals[cc];
                }
                const float inv = 1.f / s;
                #pragma unroll
                for (int cc = 0; cc < 32; ++cc)
                    r_t[cc * RST + k] = vals[cc] * inv;
            }
            __syncthreads();
        }
    }
}

extern "C" void kernel_launch(void* const* d_in, const int* in_sizes, int n_in,
                              void* d_out, int out_size, void* d_ws, size_t ws_size,
                              hipStream_t stream) {
    const float* a_in   = (const float*)d_in[0];
    const float* pose   = (const float*)d_in[1];
    const float* W      = (const float*)d_in[2];
    const float* beta_u = (const float*)d_in[3];
    const float* beta_a = (const float*)d_in[4];
    float* out = (float*)d_out;
    (void)d_ws; (void)ws_size; (void)in_sizes; (void)n_in; (void)out_size;

    em_routing_kernel<<<dim3(8 * L_), dim3(512), 0, stream>>>(
        a_in, pose, W, beta_u, beta_a, out);
}

// Round 6
// 212.896 us; speedup vs baseline: 2.4970x; 2.4970x over previous
//
#include <hip/hip_runtime.h>
#include <math.h>

// EM routing, fully fused: one block per (b, l) output position, 256 threads.
// A=32, B=32, PSIZE=16 (4x4), K=3, STRIDE=2, PAD=1, ITERS=3.
// Input 14x14 -> output 7x7 (l = 49). kkA = 9*32 = 288.
//
// LDS (64512 B total, 2 blocks/CU):
//   pu_lds[288*20]: pose patch, row k at stride 20 (80B, bank-conflict-free
//                   for ds_read_b128 across kq lanes); au[k] in pad slot 16.
//   r_t[32*292]   : holds r*au (au folded in), then ln_ap; row pad col 291
//                   carries m1[c] (ln_p const + ln a_out).
//   mu_t/is2_t[16*32]: per-(p,c) mu and 0.5/sigma^2 between P23 and P4.

#define B_      32
#define KKA_    288
#define L_      49
#define OH_     7
#define EPSF    1e-12f
#define RST     292              // padded k-stride of r_t rows
#define PUST    20               // padded p-stride of pu rows
#define LOG_LN2PI 0.60861006f    // log(log(2*pi))

__global__ __launch_bounds__(256, 2) void em_routing_kernel(
    const float* __restrict__ a_in,   // (8, 32, 14, 14)
    const float* __restrict__ pose,   // (8, 512, 14, 14)
    const float* __restrict__ W,      // (288, 32, 4, 4)
    const float* __restrict__ beta_u, // (32)
    const float* __restrict__ beta_a, // (32)
    float* __restrict__ out)          // a_o (8,32,7,7) then pose_out (8,512,7,7)
{
    __shared__ float pu_lds[KKA_ * PUST];   // 23040 B
    __shared__ float r_t[B_ * RST];         // 37376 B
    __shared__ float mu_t[16 * 32];         //  2048 B
    __shared__ float is2_t[16 * 32];        //  2048 B

    const int tid = threadIdx.x;
    const int bl = blockIdx.x;
    const int b  = bl / L_;
    const int l  = bl % L_;
    const int oy = l / OH_, ox = l % OH_;

    // ---- stage pu (pose unfold patch), stride-20 rows ----
    for (int q = tid; q < KKA_ * 16; q += 256) {
        const int k = q >> 4, p = q & 15;
        const int a = k & 31, kki = k >> 5;
        const int ki = kki / 3, kj = kki % 3;
        const int iy = oy * 2 + ki - 1, ix = ox * 2 + kj - 1;
        float v = 0.f;
        if ((unsigned)iy < 14u && (unsigned)ix < 14u)
            v = pose[(b * 512 + a * 16 + p) * 196 + iy * 14 + ix];
        pu_lds[k * PUST + p] = v;
    }
    // ---- stage au into pu pad slot 16 (strided loop: 288 > 256 threads!) ----
    for (int k = tid; k < KKA_; k += 256) {
        const int a = k & 31, kki = k >> 5;
        const int ki = kki / 3, kj = kki % 3;
        const int iy = oy * 2 + ki - 1, ix = ox * 2 + kj - 1;
        float v = 0.f;
        if ((unsigned)iy < 14u && (unsigned)ix < 14u)
            v = a_in[(b * 32 + a) * 196 + iy * 14 + ix];
        pu_lds[k * PUST + 16] = v;
    }
    __syncthreads();
    // ---- init r_t = r*au = au (r=1), pad cols = 0 ----
    for (int kk = tid; kk < RST; kk += 256) {
        const float v = (kk < KKA_) ? pu_lds[kk * PUST + 16] : 0.f;
        #pragma unroll
        for (int cc = 0; cc < B_; ++cc) r_t[cc * RST + kk] = v;
    }
    __syncthreads();

    // thread mappings
    const int c   = tid >> 3;       // 0..31  (step1 + P23)
    const int kq  = tid & 7;        // 0..7   k-slice
    const int cQ  = tid & 31;       // P4: capsule
    const int kg  = tid >> 5;       // P4: k-group 0..7

    const float bu_c = beta_u[c];
    const float ba_c = beta_a[c];
    const int rrow = c * RST;

    for (int it = 0; it < 3; ++it) {
        const float lam = (it == 0) ? 0.0005f : ((it == 1) ? 0.000975f : 0.00142625f);

        // ---- step 1: rsum[c] = sum_k r*au (no r_t writes -> no barrier) ----
        float part = 0.f;
        #pragma unroll
        for (int t = 0; t < 36; t += 4) {
            const float4 r4 = *(const float4*)&r_t[rrow + kq * 36 + t];
            part += (r4.x + r4.y) + (r4.z + r4.w);
        }
        part += __shfl_xor(part, 1);
        part += __shfl_xor(part, 2);
        part += __shfl_xor(part, 4);
        const float rsum = part;
        const float invr = 1.0f / (rsum + EPSF);

        // ---- P23: full 16-p moments, k = 8j + kq, j = 0..35 ----
        float S1[16], S2[16];
        #pragma unroll
        for (int t = 0; t < 16; ++t) { S1[t] = 0.f; S2[t] = 0.f; }
        const float* pWk = W + c * 16 + kq * 512;
        #pragma unroll 2
        for (int j = 0; j < 36; ++j) {
            const int k = (j << 3) + kq;
            const float cf = r_t[rrow + k] * invr;
            const float4 w0 = *(const float4*)(pWk);
            const float4 w1 = *(const float4*)(pWk + 4);
            const float4 w2 = *(const float4*)(pWk + 8);
            const float4 w3 = *(const float4*)(pWk + 12);
            pWk += 4096;
            const float* pk = &pu_lds[k * PUST];
            #pragma unroll
            for (int i = 0; i < 4; ++i) {
                const float4 pu4 = *(const float4*)(pk + (i << 2));
                float v, cv;
                v = pu4.x * w0.x + pu4.y * w1.x + pu4.z * w2.x + pu4.w * w3.x;
                cv = cf * v; S1[i * 4 + 0] += cv; S2[i * 4 + 0] += cv * v;
                v = pu4.x * w0.y + pu4.y * w1.y + pu4.z * w2.y + pu4.w * w3.y;
                cv = cf * v; S1[i * 4 + 1] += cv; S2[i * 4 + 1] += cv * v;
                v = pu4.x * w0.z + pu4.y * w1.z + pu4.z * w2.z + pu4.w * w3.z;
                cv = cf * v; S1[i * 4 + 2] += cv; S2[i * 4 + 2] += cv * v;
                v = pu4.x * w0.w + pu4.y * w1.w + pu4.z * w2.w + pu4.w * w3.w;
                cv = cf * v; S1[i * 4 + 3] += cv; S2[i * 4 + 3] += cv * v;
            }
        }
        // combine k-slices over the 8 kq lanes (butterfly; all lanes get sums)
        #pragma unroll
        for (int t = 0; t < 16; ++t) {
            S1[t] += __shfl_xor(S1[t], 1); S2[t] += __shfl_xor(S2[t], 1);
        }
        #pragma unroll
        for (int t = 0; t < 16; ++t) {
            S1[t] += __shfl_xor(S1[t], 2); S2[t] += __shfl_xor(S2[t], 2);
        }
        #pragma unroll
        for (int t = 0; t < 16; ++t) {
            S1[t] += __shfl_xor(S1[t], 4); S2[t] += __shfl_xor(S2[t], 4);
        }

        // ---- per-p stats: lane kq owns p = 2kq, 2kq+1 (static indices) ----
        float Lp = 0.f;
        #pragma unroll
        for (int p = 0; p < 16; ++p) {
            if ((p >> 1) == kq) {
                const float mu = S1[p];
                const float ss = fmaxf(S2[p] - mu * mu, 0.f) + EPSF;
                Lp += __logf(ss);
                if (it == 2) {
                    out[12544 + (b * 512 + (c << 4) + p) * 49 + l] = mu;
                } else {
                    mu_t[p * 32 + c]  = mu;
                    is2_t[p * 32 + c] = 0.5f / ss;
                }
            }
        }
        float Ls = Lp;
        Ls += __shfl_xor(Ls, 1);
        Ls += __shfl_xor(Ls, 2);
        Ls += __shfl_xor(Ls, 4);                 // sum_p log(ss)
        const float cost = rsum * (16.f * bu_c + 0.5f * Ls);
        const float aout = 1.f / (1.f + __expf(-(lam * (ba_c - cost))));

        if (it == 2) {
            if (kq == 0) out[(b * 32 + c) * 49 + l] = aout;
        } else {
            if (kq == 0)
                r_t[rrow + 291] = -0.5f * (Ls + 16.f * LOG_LN2PI) + __logf(aout);
            __syncthreads();

            // ---- P4: ln_ap[k][c] -> r_t  (kg = 0..7, k = kg + 8j) ----
            float mu_r[16], is2_r[16];
            #pragma unroll
            for (int p = 0; p < 16; ++p) {
                mu_r[p]  = mu_t[p * 32 + cQ];
                is2_r[p] = is2_t[p * 32 + cQ];
            }
            const float m1c = r_t[cQ * RST + 291];
            const float* pW4 = W + kg * 512 + cQ * 16;
            #pragma unroll 2
            for (int j = 0; j < 36; ++j) {
                const int k = kg + (j << 3);
                const float4 wr0 = *(const float4*)(pW4);
                const float4 wr1 = *(const float4*)(pW4 + 4);
                const float4 wr2 = *(const float4*)(pW4 + 8);
                const float4 wr3 = *(const float4*)(pW4 + 12);
                pW4 += 4096;
                float q = 0.f;
                #pragma unroll
                for (int i = 0; i < 4; ++i) {
                    const float4 pui = *(const float4*)&pu_lds[k * PUST + (i << 2)];
                    float vv, d;
                    vv = pui.x * wr0.x + pui.y * wr1.x + pui.z * wr2.x + pui.w * wr3.x;
                    d = vv - mu_r[i * 4 + 0]; q += d * d * is2_r[i * 4 + 0];
                    vv = pui.x * wr0.y + pui.y * wr1.y + pui.z * wr2.y + pui.w * wr3.y;
                    d = vv - mu_r[i * 4 + 1]; q += d * d * is2_r[i * 4 + 1];
                    vv = pui.x * wr0.z + pui.y * wr1.z + pui.z * wr2.z + pui.w * wr3.z;
                    d = vv - mu_r[i * 4 + 2]; q += d * d * is2_r[i * 4 + 2];
                    vv = pui.x * wr0.w + pui.y * wr1.w + pui.z * wr2.w + pui.w * wr3.w;
                    d = vv - mu_r[i * 4 + 3]; q += d * d * is2_r[i * 4 + 3];
                }
                r_t[cQ * RST + k] = m1c - q;
            }
            __syncthreads();

            // ---- softmax over c per k; fold au back in on write ----
            for (int k = tid; k < KKA_; k += 256) {
                float vals[32];
                float mx = -3.0e38f;
                #pragma unroll
                for (int cc = 0; cc < 32; ++cc) {
                    vals[cc] = r_t[cc * RST + k];
                    mx = fmaxf(mx, vals[cc]);
                }
                float s = 0.f;
                #pragma unroll
                for (int cc = 0; cc < 32; ++cc) {
                    vals[cc] = __expf(vals[cc] - mx);
                    s += vals[cc];
                }
                const float sc = pu_lds[k * PUST + 16] / s;   // au[k]/sum
                #pragma unroll
                for (int cc = 0; cc < 32; ++cc)
                    r_t[cc * RST + k] = vals[cc] * sc;
            }
            __syncthreads();
        }
    }
}

extern "C" void kernel_launch(void* const* d_in, const int* in_sizes, int n_in,
                              void* d_out, int out_size, void* d_ws, size_t ws_size,
                              hipStream_t stream) {
    const float* a_in   = (const float*)d_in[0];
    const float* pose   = (const float*)d_in[1];
    const float* W      = (const float*)d_in[2];
    const float* beta_u = (const float*)d_in[3];
    const float* beta_a = (const float*)d_in[4];
    float* out = (float*)d_out;
    (void)d_ws; (void)ws_size; (void)in_sizes; (void)n_in; (void)out_size;

    em_routing_kernel<<<dim3(8 * L_), dim3(256), 0, stream>>>(
        a_in, pose, W, beta_u, beta_a, out);
}